// Round 4
// baseline (205.067 us; speedup 1.0000x reference)
//
#include <hip/hip_runtime.h>
#include <hip/hip_bf16.h>

typedef __attribute__((ext_vector_type(4))) int i32x4;

#define M_DIM 8192
#define N_DIM 8192
#define K_DIM 2048
#define BK 128                   // i8 K-bytes per K-tile
#define WCOUNT (N_DIM * K_DIM)   // 16,777,216 weight elements

// ---------------- kernel 1: per-block partial sums of |w| ----------------
__global__ __launch_bounds__(256) void k_abs_partial(const float* __restrict__ w,
                                                     float* __restrict__ part) {
    int tid = blockIdx.x * 256 + threadIdx.x;
    const float4* w4 = (const float4*)w;
    float s = 0.0f;
    const int total4 = WCOUNT / 4;
    for (int i = tid; i < total4; i += 2048 * 256) {
        float4 v = w4[i];
        s += fabsf(v.x) + fabsf(v.y) + fabsf(v.z) + fabsf(v.w);
    }
    #pragma unroll
    for (int off = 1; off < 64; off <<= 1) s += __shfl_xor(s, off);
    __shared__ float red[4];
    if ((threadIdx.x & 63) == 0) red[threadIdx.x >> 6] = s;
    __syncthreads();
    if (threadIdx.x == 0)
        part[blockIdx.x] = (red[0] + red[1]) + (red[2] + red[3]);
}

// ---------------- kernel 2: deterministic final reduce -> sum|w| ----------------
__global__ __launch_bounds__(256) void k_abs_final(const float* __restrict__ part,
                                                   float* __restrict__ sum) {
    int t = threadIdx.x;
    float s = 0.0f;
    #pragma unroll
    for (int i = 0; i < 8; i++) s += part[t + i * 256];
    #pragma unroll
    for (int off = 1; off < 64; off <<= 1) s += __shfl_xor(s, off);
    __shared__ float red[4];
    if ((t & 63) == 0) red[t >> 6] = s;
    __syncthreads();
    if (t == 0) sum[0] = (red[0] + red[1]) + (red[2] + red[3]);
}

// ---------------- kernel 3: ternary weight quant -> int8 {-1,0,1} ----------------
__global__ __launch_bounds__(256) void k_wquant(const float* __restrict__ w,
                                                const float* __restrict__ sum,
                                                unsigned int* __restrict__ wq) {
    const float thr = 0.5f * (sum[0] * (1.0f / 16777216.0f));
    int tid = blockIdx.x * 256 + threadIdx.x;
    const float4* w4 = (const float4*)w;
    const int total4 = WCOUNT / 4;
    for (int i = tid; i < total4; i += 2048 * 256) {
        float4 v = w4[i];
        union { signed char c[4]; unsigned int u; } q;
        q.c[0] = v.x > thr ? 1 : (v.x < -thr ? -1 : 0);
        q.c[1] = v.y > thr ? 1 : (v.y < -thr ? -1 : 0);
        q.c[2] = v.z > thr ? 1 : (v.z < -thr ? -1 : 0);
        q.c[3] = v.w > thr ? 1 : (v.w < -thr ? -1 : 0);
        wq[i] = q.u;
    }
}

// ---------------- kernel 4: per-row activation quant -> int8 + scale ----------------
__global__ __launch_bounds__(256) void k_xquant(const float* __restrict__ x,
                                                signed char* __restrict__ xq,
                                                float* __restrict__ scale) {
    const int row = blockIdx.x;
    const int t = threadIdx.x;
    const float4* xr = (const float4*)(x + (size_t)row * K_DIM);
    float4 a = xr[t * 2];
    float4 b = xr[t * 2 + 1];
    float m = fmaxf(fmaxf(fmaxf(fabsf(a.x), fabsf(a.y)), fmaxf(fabsf(a.z), fabsf(a.w))),
                    fmaxf(fmaxf(fabsf(b.x), fabsf(b.y)), fmaxf(fabsf(b.z), fabsf(b.w))));
    #pragma unroll
    for (int off = 1; off < 64; off <<= 1) m = fmaxf(m, __shfl_xor(m, off));
    __shared__ float red[4];
    if ((t & 63) == 0) red[t >> 6] = m;
    __syncthreads();
    m = fmaxf(fmaxf(red[0], red[1]), fmaxf(red[2], red[3]));
    const float sc = fmaxf(m, 1e-5f);
    if (t == 0) scale[row] = sc;
    const float r = 127.0f / sc;
    float q[8] = {a.x, a.y, a.z, a.w, b.x, b.y, b.z, b.w};
    union { signed char c[8]; uint2 v; } pk;
    #pragma unroll
    for (int j = 0; j < 8; j++) {
        float v = rintf(q[j] * r);
        v = fminf(fmaxf(v, -127.0f), 127.0f);
        pk.c[j] = (signed char)v;
    }
    *(uint2*)(xq + (size_t)row * K_DIM + t * 8) = pk.v;
}

// ---------------- kernel 5: 256x256 8-phase i8 MFMA GEMM (template-faithful) ----
// A = x_q [M][K] i8, B = w_q [N][K] i8, out[M][N] fp32 = relu(acc*coef)^2.
// 512 thr / 8 waves (2Mx4N). LDS 128 KiB: 2 buffers x (A 32K + B 32K), half = 128
// rows x 128 B. Swizzle: slot s of row r holds chunk g = s ^ ((r>>1)&7) (inverse-
// swizzled global source, linear LDS dest, swizzled read — rule 21).
// Phase = { 1 STG | ds_reads | [lgkm8] | BAR | lgkm0 | setprio 16xMFMA | BAR }.
// Stage ring (iter i: buf0=kt2i read ph1-3, buf1=kt2i+1 read ph5-7):
//   ph1: B1h1(kt+1)  ph2: A1h0(kt+1)  ph3: A1h1(kt+1)  ph4: B0h0(kt+2)
//   ph5: B0h1(kt+2)  ph6: A0h0(kt+2)  ph7: A0h1(kt+2)  ph8: B1h0(kt+3)
// vmcnt(2) at end of ph4 (gates buf1 reads at ph5) and ph8 (gates next buf0 reads).
// WAR: every restage is >=2 barriers after the region's last ds_read completes.
#define GLDS16(g, l)                                                                   \
    __builtin_amdgcn_global_load_lds((const __attribute__((address_space(1))) void*)(g), \
                                     (__attribute__((address_space(3))) void*)(l), 16, 0, 0)

#define AOFF(b, h) ((b) * 32768 + (h) * 16384)
#define BOFF(b, h) (65536 + (b) * 32768 + (h) * 16384)
#define BAR __builtin_amdgcn_s_barrier()
#define LGKM8 do { asm volatile("s_waitcnt lgkmcnt(8)" ::: "memory"); __builtin_amdgcn_sched_barrier(0); } while (0)
#define LGKM0 do { asm volatile("s_waitcnt lgkmcnt(0)" ::: "memory"); __builtin_amdgcn_sched_barrier(0); } while (0)
#define VMCNT2 do { asm volatile("s_waitcnt vmcnt(2)" ::: "memory"); __builtin_amdgcn_sched_barrier(0); } while (0)
#define VMCNT0 do { asm volatile("s_waitcnt vmcnt(0)" ::: "memory"); __builtin_amdgcn_sched_barrier(0); } while (0)

__global__ __launch_bounds__(512, 2) void k_gemm(const signed char* __restrict__ Aq,
                                                 const signed char* __restrict__ Bq,
                                                 const float* __restrict__ scale,
                                                 const float* __restrict__ sum,
                                                 float* __restrict__ out) {
    __shared__ signed char lds[131072];

    const int t = threadIdx.x;
    const int lane = t & 63;
    const int wid = t >> 6;        // 0..7
    const int wm = wid >> 2;       // 0..1  (M half)
    const int wn = wid & 3;        // 0..3  (N quarter)
    const int lane4 = lane & 15;
    const int hi = lane >> 4;

    // L2-aware mapping: XCD x owns brow in [4x,4x+4); per XCD, 8 super-tiles of
    // 4x4 blocks sweep bcol. A panels (2MB) stay L2-resident; B streams 4-at-a-time.
    const int bid = blockIdx.x;
    const int xcd = bid & 7;
    const int s_ = bid >> 3;          // 0..127
    const int scol = s_ >> 4;         // 0..7
    const int w_ = s_ & 15;
    const int brow = xcd * 4 + (w_ >> 2);
    const int bcol = scol * 4 + (w_ & 3);

    // ---- staging geometry: thread t owns chunk c0=t (rows 0..63) and c1=t+512
    // (rows 64..127) of a 128-row half-tile; global k-chunk inverse-swizzled.
    const int r0 = t >> 3;
    const int g0 = ((t & 7) ^ ((t >> 4) & 7)) << 4;
    const int g1 = (((t + 512) & 7) ^ (((t + 512) >> 4) & 7)) << 4;
    const int sa0 = r0 * K_DIM + g0;          // + half*128*K_DIM + kt*BK
    const int sa1 = (64 + r0) * K_DIM + g1;
    const int dst0 = wid * 1024;              // + lane*16 implicit
    const int dst1 = wid * 1024 + 8192;

    const signed char* Abase = Aq + (size_t)(brow * 256) * K_DIM;
    const signed char* Bbase = Bq + (size_t)(bcol * 256) * K_DIM;

#define STG(gb, ldsoff, half, kt) do {                                                  \
        GLDS16((gb) + (half) * (128 * K_DIM) + (kt) * BK + sa0, lds + (ldsoff) + dst0); \
        GLDS16((gb) + (half) * (128 * K_DIM) + (kt) * BK + sa1, lds + (ldsoff) + dst1); \
    } while (0)

    // ---- fragment read bases; swizzled slot = (ks*4+hi) ^ (lane4>>1)
    const int swz0 = (hi ^ (lane4 >> 1)) << 4;
    const int swz1 = ((4 + hi) ^ (lane4 >> 1)) << 4;
    const int aB0 = AOFF(0, wm) + lane4 * 128;
    const int aB1 = AOFF(1, wm) + lane4 * 128;
    const int bB0 = BOFF(0, wn >> 1) + ((wn & 1) * 64 + lane4) * 128;
    const int bB1 = BOFF(1, wn >> 1) + ((wn & 1) * 64 + lane4) * 128;

    i32x4 acc[8][4];
    #pragma unroll
    for (int m = 0; m < 8; m++)
        #pragma unroll
        for (int n = 0; n < 4; n++) acc[m][n] = (i32x4){0, 0, 0, 0};
    i32x4 fa0[8], fa1[8], fb0[4], fb1[4];

#define RDA4(mlo, base) do { _Pragma("unroll") for (int m_ = 0; m_ < 4; m_++) {         \
        fa0[(mlo) + m_] = *(const i32x4*)&lds[(base) + ((mlo) + m_) * 2048 + swz0];     \
        fa1[(mlo) + m_] = *(const i32x4*)&lds[(base) + ((mlo) + m_) * 2048 + swz1]; } } while (0)
#define RDB2(nlo, base) do { _Pragma("unroll") for (int n_ = 0; n_ < 2; n_++) {         \
        fb0[(nlo) + n_] = *(const i32x4*)&lds[(base) + ((nlo) + n_) * 2048 + swz0];     \
        fb1[(nlo) + n_] = *(const i32x4*)&lds[(base) + ((nlo) + n_) * 2048 + swz1]; } } while (0)
#define MM(mlo, nlo) do { __builtin_amdgcn_s_setprio(1);                                \
        _Pragma("unroll") for (int m_ = 0; m_ < 4; m_++)                                \
        _Pragma("unroll") for (int n_ = 0; n_ < 2; n_++) {                              \
            acc[(mlo) + m_][(nlo) + n_] = __builtin_amdgcn_mfma_i32_16x16x64_i8(        \
                fa0[(mlo) + m_], fb0[(nlo) + n_], acc[(mlo) + m_][(nlo) + n_], 0, 0, 0);\
            acc[(mlo) + m_][(nlo) + n_] = __builtin_amdgcn_mfma_i32_16x16x64_i8(        \
                fa1[(mlo) + m_], fb1[(nlo) + n_], acc[(mlo) + m_][(nlo) + n_], 0, 0, 0);\
        } __builtin_amdgcn_s_setprio(0); } while (0)

    // ---- prologue: buf0 <- kt0 (B-h0,B-h1,A-h0,A-h1), buf1 B-h0 <- kt1; gate buf0.
    STG(Bbase, BOFF(0, 0), 0, 0);
    STG(Bbase, BOFF(0, 1), 1, 0);
    STG(Abase, AOFF(0, 0), 0, 0);
    STG(Abase, AOFF(0, 1), 1, 0);
    STG(Bbase, BOFF(1, 0), 0, 1);
    VMCNT2;
    BAR;

    #pragma unroll 1
    for (int i = 0; i < 8; i++) {
        const int kt = 2 * i;
        // ph1: Q1(buf0) -- reads A0-3, B0-1 (12)
        STG(Bbase, BOFF(1, 1), 1, kt + 1);
        RDA4(0, aB0); RDB2(0, bB0);
        LGKM8;
        BAR; LGKM0;
        MM(0, 0);
        BAR;
        // ph2: Q3(buf0) -- reads B2-3 (4)
        STG(Abase, AOFF(1, 0), 0, kt + 1);
        RDB2(2, bB0);
        BAR; LGKM0;
        MM(0, 2);
        BAR;
        // ph3: Q2(buf0) -- reads A4-7 (8)
        STG(Abase, AOFF(1, 1), 1, kt + 1);
        RDA4(4, aB0);
        BAR; LGKM0;
        MM(4, 0);
        BAR;
        // ph4: Q4(buf0) -- no reads; gate buf1
        if (i < 7) STG(Bbase, BOFF(0, 0), 0, kt + 2);
        MM(4, 2);
        if (i < 7) VMCNT2; else VMCNT0;
        BAR;
        // ph5: Q1(buf1) -- reads A0-3, B0-1 (12)
        if (i < 7) STG(Bbase, BOFF(0, 1), 1, kt + 2);
        RDA4(0, aB1); RDB2(0, bB1);
        LGKM8;
        BAR; LGKM0;
        MM(0, 0);
        BAR;
        // ph6: Q3(buf1) -- reads B2-3 (4)
        if (i < 7) STG(Abase, AOFF(0, 0), 0, kt + 2);
        RDB2(2, bB1);
        BAR; LGKM0;
        MM(0, 2);
        BAR;
        // ph7: Q2(buf1) -- reads A4-7 (8)
        if (i < 7) STG(Abase, AOFF(0, 1), 1, kt + 2);
        RDA4(4, aB1);
        BAR; LGKM0;
        MM(4, 0);
        BAR;
        // ph8: Q4(buf1) -- no reads; gate next buf0
        if (i < 7) STG(Bbase, BOFF(1, 0), 0, kt + 3);
        MM(4, 2);
        if (i < 7) VMCNT2;
        BAR;
    }

    // ---- epilogue: out = (max(acc * w_scale / scale_row, 0))^2
    const float wsc = sum[0] * (1.0f / 16777216.0f);
    const int rb = brow * 256 + wm * 128 + hi * 4;
    const int cb = bcol * 256 + wn * 64 + lane4;
    #pragma unroll
    for (int m = 0; m < 8; m++) {
        #pragma unroll
        for (int j = 0; j < 4; j++) {
            const int grow = rb + m * 16 + j;
            const float coef = wsc / scale[grow];
            #pragma unroll
            for (int n = 0; n < 4; n++) {
                float v = (float)acc[m][n][j] * coef;   // C/D: col=lane&15, row=hi*4+j
                v = fmaxf(v, 0.0f);
                out[(size_t)grow * N_DIM + cb + n * 16] = v * v;
            }
        }
    }
#undef STG
#undef RDA4
#undef RDB2
#undef MM
}

// ---------------- launch ----------------
extern "C" void kernel_launch(void* const* d_in, const int* in_sizes, int n_in,
                              void* d_out, int out_size, void* d_ws, size_t ws_size,
                              hipStream_t stream) {
    const float* x = (const float*)d_in[0];   // [4,2048,2048] fp32
    const float* w = (const float*)d_in[1];   // [8192,2048] fp32
    float* out = (float*)d_out;               // [4,2048,8192] fp32

    char* ws = (char*)d_ws;
    float* sum   = (float*)ws;                 // 1 float
    float* part  = (float*)(ws + 256);         // 2048 floats
    float* scale = (float*)(ws + 16384);       // 8192 floats
    signed char* xq = (signed char*)(ws + 65536);              // 16.78 MB i8
    signed char* wq = (signed char*)(ws + 65536 + 16777216);   // 16.78 MB i8

    k_abs_partial<<<2048, 256, 0, stream>>>(w, part);
    k_abs_final<<<1, 256, 0, stream>>>(part, sum);
    k_wquant<<<2048, 256, 0, stream>>>(w, sum, (unsigned int*)wq);
    k_xquant<<<M_DIM, 256, 0, stream>>>(x, xq, scale);
    k_gemm<<<dim3(1024), 512, 0, stream>>>(xq, wq, scale, sum, out);
}